// Round 1
// baseline (23777.644 us; speedup 1.0000x reference)
//
#include <hip/hip_runtime.h>
#include <cstdint>
#include <cstddef>

// Problem constants (match reference)
#define B_    64
#define C_    128
#define T_    500
#define NRES  2048
#define NCLS  10

// Kernel org: 256 wgs (one per CU), 1024 threads.
// tid = wid*64 + b ; wid = halfb*8 + il ; lanes = batches.
// Thread pair (b, il, half0/half1) splits the K=2048 sum:
//   half0: blocks 0,1 (j 0..1023)      half1: blocks 2,3 (j 1024..2047) + G1
// half1 publishes {a2, a3, g1} via LDS; half0 performs the exact original
// fold ((a0+a1)+a2)+a3 and the LIF update. 16 waves/CU (was 8).
#define NWG   256
#define SL    8
#define NT    1024

// BIT-EXACT MODEL (validated r10-r12, absmax 0.0): np reference = AOCL/BLIS f32
// chain. G1: ascending fmaf chain (K=128, one block). G2: KC=512 blocks
// [512,512,512,512], each an ascending masked rn-add chain starting at 0,
// folded left-to-right ((b0+b1)+b2)+b3. LIF: v = rn(rn(0.9f*v) + rn(g1+g2)).
// DO NOT CHANGE THE ARITHMETIC. (K-split across threads preserves each
// 512-block chain order and the fold order exactly.)

// Weights (W_res rows, W_in rows) are read directly from global memory:
// wave-uniform addresses on read-only __restrict__ data -> scalar/L2-coalesced
// loads, freeing the LDS pipe (which previously carried ~512 b128 broadcast
// reads per thread-step) and 68 KB of LDS.

// d_ws layout: [0,16384) mask buf0, [16384,32768) mask buf1,
//              [32768,+4) arrival counter, [33024,+4) release flag
#define WS_MASK0   0
#define WS_MASK1   16384
#define WS_CNT     32768
#define WS_FLAG    33024
#define WS_WORDS   8320    // zero through 33280 B (covers masks+cnt+flag)

struct SMem {
  float    xs[B_][C_ + 1];          // 33024 B : x[:, :, t], row-padded
  unsigned mask[B_][65];            // 16640 B : spike bits s(t-1), row-padded
  float    part[SL][B_][5];         // 10240 B : {a2, a3, g1} per (il, b), pad 5
  unsigned long long balls[SL];     //    64 B : per-wave spike ballots (half0)
  double   clfred[16][NCLS];        //  1280 B : classifier per-wave partials
};                                   // total ~61 KB => 1 wg/CU (grid = 256)

__global__ void zero_ws_kernel(unsigned* __restrict__ p, int n) {
  int i = blockIdx.x * blockDim.x + threadIdx.x;
  if (i < n) p[i] = 0u;
}

// ascending-j masked add into chain A; bfe(sign-extend bit) + and + fadd
#define ACC1(A, W, M, JB) \
  (A) = __fadd_rn((A), __uint_as_float((unsigned)(((int)((M) << (31 - (JB)))) >> 31) & __float_as_uint(W)))

__global__ void __launch_bounds__(NT, 4)
reservoir_kernel(const float* __restrict__ x, const float* __restrict__ Win,
                 const float* __restrict__ Wres, const float* __restrict__ Wclf,
                 float* __restrict__ out, unsigned char* __restrict__ ws) {
  __shared__ SMem sm;
  const int w     = blockIdx.x;
  const int tid   = threadIdx.x;
  const int b     = tid & 63;        // lane = batch
  const int wid   = tid >> 6;        // wave index 0..15
  const int il    = wid & 7;         // local neuron index
  const int halfb = wid >> 3;        // 0: blocks 0,1 + LIF ; 1: blocks 2,3 + G1
  const int iu    = __builtin_amdgcn_readfirstlane(w * SL + il);
  const float* __restrict__ wgrow   = Wres + (size_t)iu * NRES + halfb * 1024;
  const float* __restrict__ win_row = Win  + (size_t)iu * C_;

  unsigned* mbuf0 = (unsigned*)(ws + WS_MASK0);
  unsigned* mbuf1 = (unsigned*)(ws + WS_MASK1);
  unsigned* cnt   = (unsigned*)(ws + WS_CNT);
  unsigned* flag  = (unsigned*)(ws + WS_FLAG);

  // ---- one-time: cache this thread's 20 Wclf values in VGPRs ----
  float wcf[NCLS * 2];
  {
    const int j0 = tid * 2;
    #pragma unroll
    for (int c2 = 0; c2 < NCLS; ++c2)
      #pragma unroll
      for (int jj = 0; jj < 2; ++jj)
        wcf[c2 * 2 + jj] = Wclf[(size_t)c2 * NRES + j0 + jj];
  }

  // persistent state: EXACT replica of the np float32 trajectory
  float v = 0.f;                   // reservoir membrane (half0 threads only)
  int   cntr = 0;
  double vc = 0.0;                 // classifier membrane (no feedback -> f64 ok)
  int   cntc = 0;

  // prefetch x(:,:,0): flat pair p = tid*8 + r, p = b*C_ + c
  float xv[8];
  {
    const int p0 = tid * 8;
    #pragma unroll
    for (int r = 0; r < 8; ++r) xv[r] = x[(size_t)(p0 + r) * T_ + 0];
  }

  for (int t = 0; t < T_; ++t) {
    unsigned* prevm = (t & 1) ? mbuf0 : mbuf1;   // s(t-1); t=0 reads zeroed buf1
    unsigned char* curm = (unsigned char*)((t & 1) ? mbuf1 : mbuf0);

    // ---- stage prev spike masks (coherent atomic loads -> LDS) ----
    unsigned mm[4];
    {
      const int k0 = tid * 4;
      #pragma unroll
      for (int r = 0; r < 4; ++r)
        mm[r] = __hip_atomic_load(prevm + k0 + r, __ATOMIC_RELAXED,
                                  __HIP_MEMORY_SCOPE_AGENT);
    }
    // ---- xs <- xv (x for this step, staged from prefetch regs) ----
    {
      const int p0 = tid * 8;
      #pragma unroll
      for (int r = 0; r < 8; ++r) {
        int p = p0 + r;
        sm.xs[p >> 7][p & 127] = xv[r];
      }
    }
    {
      const int k0 = tid * 4;
      #pragma unroll
      for (int r = 0; r < 4; ++r) {
        int k = k0 + r;
        sm.mask[k >> 6][k & 63] = mm[r];
      }
    }
    __syncthreads();  // A: xs + mask ready

    // ---- prefetch next step's x ----
    if (t + 1 < T_) {
      const int p0 = tid * 8;
      #pragma unroll
      for (int r = 0; r < 8; ++r) xv[r] = x[(size_t)(p0 + r) * T_ + (t + 1)];
    }

    // ---- G1 (half1 only): feedforward, pure f32 fma chain c=0..127 ----
    float g1 = 0.f;
    if (halfb) {
      const float4* __restrict__ winp = (const float4*)win_row;  // uniform
      #pragma unroll 8
      for (int cq = 0; cq < 32; ++cq) {
        const float4 wv = winp[cq];
        const int c = cq * 4;
        g1 = fmaf(sm.xs[b][c + 0], wv.x, g1);
        g1 = fmaf(sm.xs[b][c + 1], wv.y, g1);
        g1 = fmaf(sm.xs[b][c + 2], wv.z, g1);
        g1 = fmaf(sm.xs[b][c + 3], wv.w, g1);
      }
    }

    // ---- G2 half: two independent KC=512 block chains, interleaved ----
    float aA = 0.f, aB = 0.f;
    {
      const unsigned* mrow = &sm.mask[b][0];
      const int mo = halfb * 32;
      for (int wq = 0; wq < 16; ++wq) {
        unsigned mwA = mrow[mo + wq];
        unsigned mwB = mrow[mo + 16 + wq];
        const float4* __restrict__ qA = (const float4*)(wgrow + wq * 32);
        const float4* __restrict__ qB = (const float4*)(wgrow + 512 + wq * 32);
        #pragma unroll
        for (int jq = 0; jq < 8; ++jq) {
          const float4 wA = qA[jq];
          const float4 wB = qB[jq];
          const int jb = jq * 4;
          ACC1(aA, wA.x, mwA, jb + 0); ACC1(aA, wA.y, mwA, jb + 1);
          ACC1(aA, wA.z, mwA, jb + 2); ACC1(aA, wA.w, mwA, jb + 3);
          ACC1(aB, wB.x, mwB, jb + 0); ACC1(aB, wB.y, mwB, jb + 1);
          ACC1(aB, wB.z, mwB, jb + 2); ACC1(aB, wB.w, mwB, jb + 3);
        }
      }
    }

    // ---- half1 publishes partials {a2, a3, g1} ----
    if (halfb) {
      sm.part[il][b][0] = aA;
      sm.part[il][b][1] = aB;
      sm.part[il][b][2] = g1;
    }
    __syncthreads();  // E: partials ready

    // ---- half0: exact fold + LIF update + ballot ----
    if (!halfb) {
      const float a2  = sm.part[il][b][0];
      const float a3  = sm.part[il][b][1];
      const float g1p = sm.part[il][b][2];
      // fold order identical to r10-r12: ((blk0 + blk1) + blk2) + blk3
      float g2 = __fadd_rn(__fadd_rn(__fadd_rn(aA, aB), a2), a3);
      float I  = __fadd_rn(g1p, g2);
      v = __fadd_rn(__fmul_rn(0.9f, v), I);
      bool s = (v >= 1.0f);
      if (s) { v = 0.f; cntr++; }
      unsigned long long bal = __ballot(s);  // bit b = spike(batch b, neuron iu)
      if (b == 0) sm.balls[il] = bal;
    }
    __syncthreads();  // B: balls ready

    // ---- assemble and store this wg's spike bytes (coherent atomic store) ----
    if (tid < B_) {
      unsigned byte = 0;
      #pragma unroll
      for (int il2 = 0; il2 < SL; ++il2)
        byte |= ((unsigned)((sm.balls[il2] >> tid) & 1ull)) << il2;
      __hip_atomic_store(curm + tid * 256 + w, (unsigned char)byte,
                         __ATOMIC_RELAXED, __HIP_MEMORY_SCOPE_AGENT);
    }
    __syncthreads();  // B2: all mask stores drained before arrival

    // ---- ARRIVE early: counter line is never polled; last arriver raises flag ----
    if (tid == 0) {
      unsigned old = __hip_atomic_fetch_add(cnt, 1u, __ATOMIC_RELEASE,
                                            __HIP_MEMORY_SCOPE_AGENT);
      unsigned tgt = (unsigned)(t + 1) * NWG;
      if (old == tgt - 1u)
        __hip_atomic_store(flag, (unsigned)(t + 1), __ATOMIC_RELEASE,
                           __HIP_MEMORY_SCOPE_AGENT);
    }

    // ---- classifier partials for s(t-1) DURING the poll window (wg<64) ----
    if (w < B_) {
      double pc[NCLS];
      #pragma unroll
      for (int c2 = 0; c2 < NCLS; ++c2) pc[c2] = 0.0;
      if (t > 0) {
        const int j0 = tid * 2;
        unsigned mw = sm.mask[w][j0 >> 5];
        #pragma unroll
        for (int jj = 0; jj < 2; ++jj) {
          if ((mw >> ((j0 + jj) & 31)) & 1u) {
            #pragma unroll
            for (int c2 = 0; c2 < NCLS; ++c2)
              pc[c2] += (double)wcf[c2 * 2 + jj];
          }
        }
      }
      #pragma unroll
      for (int off = 1; off < 64; off <<= 1) {
        #pragma unroll
        for (int c2 = 0; c2 < NCLS; ++c2)
          pc[c2] += __shfl_xor(pc[c2], off, 64);
      }
      if ((tid & 63) == 0) {
        int wv = tid >> 6;
        #pragma unroll
        for (int c2 = 0; c2 < NCLS; ++c2) sm.clfred[wv][c2] = pc[c2];
      }
    }
    __syncthreads();  // C: clfred ready

    // ---- classifier LIF update (wg<64, tid<10) ----
    if (w < B_ && tid < NCLS) {
      double sc = 0.0;
      #pragma unroll
      for (int q2 = 0; q2 < 16; ++q2) sc += sm.clfred[q2][tid];
      vc = 0.9 * vc + sc;
      if (vc >= 1.0) { vc = 0.0; cntc++; }
    }

    // ---- poll the release flag (read-shared line, no RMW interference) ----
    if (tid == 0) {
      while (__hip_atomic_load(flag, __ATOMIC_RELAXED,
                               __HIP_MEMORY_SCOPE_AGENT) < (unsigned)(t + 1))
        __builtin_amdgcn_s_sleep(1);
    }
    __syncthreads();  // D: whole wg proceeds past the grid barrier
  }

  // ---- epilogue: classifier step for s(T-1) (in buf1 since 499&1==1) ----
  if (w < B_ && tid < 64)
    sm.mask[w][tid] = __hip_atomic_load(mbuf1 + w * 64 + tid, __ATOMIC_RELAXED,
                                        __HIP_MEMORY_SCOPE_AGENT);
  __syncthreads();
  if (w < B_) {
    double pc[NCLS];
    #pragma unroll
    for (int c2 = 0; c2 < NCLS; ++c2) pc[c2] = 0.0;
    const int j0 = tid * 2;
    unsigned mw = sm.mask[w][j0 >> 5];
    #pragma unroll
    for (int jj = 0; jj < 2; ++jj) {
      if ((mw >> ((j0 + jj) & 31)) & 1u) {
        #pragma unroll
        for (int c2 = 0; c2 < NCLS; ++c2)
          pc[c2] += (double)wcf[c2 * 2 + jj];
      }
    }
    #pragma unroll
    for (int off = 1; off < 64; off <<= 1) {
      #pragma unroll
      for (int c2 = 0; c2 < NCLS; ++c2)
        pc[c2] += __shfl_xor(pc[c2], off, 64);
    }
    if ((tid & 63) == 0) {
      int wv = tid >> 6;
      #pragma unroll
      for (int c2 = 0; c2 < NCLS; ++c2) sm.clfred[wv][c2] = pc[c2];
    }
  }
  __syncthreads();
  if (w < B_ && tid < NCLS) {
    double sc = 0.0;
    #pragma unroll
    for (int q2 = 0; q2 < 16; ++q2) sc += sm.clfred[q2][tid];
    vc = 0.9 * vc + sc;
    if (vc >= 1.0) cntc++;
    out[w * NCLS + tid] = (float)cntc;
  }
  // ---- reservoir spike counts: half0 thread (b, il) owns (b, iu) ----
  if (halfb == 0)
    out[B_ * NCLS + (size_t)b * NRES + w * SL + il] = (float)cntr;
}

extern "C" void kernel_launch(void* const* d_in, const int* in_sizes, int n_in,
                              void* d_out, int out_size, void* d_ws, size_t ws_size,
                              hipStream_t stream) {
  const float* x    = (const float*)d_in[0];   // (B, C, T)
  const float* Win  = (const float*)d_in[1];   // (NRES, C)
  const float* Wres = (const float*)d_in[2];   // (NRES, NRES)
  const float* Wclf = (const float*)d_in[3];   // (NCLS, NRES)
  float* out = (float*)d_out;
  unsigned char* ws = (unsigned char*)d_ws;

  hipLaunchKernelGGL(zero_ws_kernel, dim3((WS_WORDS + 255) / 256), dim3(256), 0, stream,
                     (unsigned*)ws, WS_WORDS);
  hipLaunchKernelGGL(reservoir_kernel, dim3(NWG), dim3(NT), 0, stream,
                     x, Win, Wres, Wclf, out, ws);
}

// Round 2
// 18049.229 us; speedup vs baseline: 1.3174x; 1.3174x over previous
//
#include <hip/hip_runtime.h>
#include <cstdint>
#include <cstddef>

// Problem constants (match reference)
#define B_    64
#define C_    128
#define T_    500
#define NRES  2048
#define NCLS  10

// Kernel org: 256 wgs (one per CU), 1024 threads.
// tid = wid*64 + b ; wid = halfb*8 + il ; lanes = batches.
// Thread pair (b, il, half0/half1) splits the K=2048 sum:
//   half0: blocks 0,1 (j 0..1023)      half1: blocks 2,3 (j 1024..2047) + G1
// half1 publishes {a2, a3, g1} via LDS; half0 performs the exact original
// fold ((a0+a1)+a2)+a3 and the LIF update. 16 waves/CU.
#define NWG   256
#define SL    8
#define NT    1024

// BIT-EXACT MODEL (validated r10-r12 + r1 split, absmax 0.0): np reference =
// AOCL/BLIS f32 chain. G1: ascending fmaf chain (K=128, one block). G2: KC=512
// blocks [512,512,512,512], each an ascending masked rn-add chain starting at
// 0, folded left-to-right ((b0+b1)+b2)+b3. LIF: v = rn(rn(0.9f*v) + rn(g1+g2)).
// DO NOT CHANGE THE ARITHMETIC. (K-split across threads preserves each
// 512-block chain order and the fold order exactly.)

// r2 changes vs r1:
//  - W_res/W_in staged in LDS again (r1's global-weight reads thrashed L2:
//    FETCH_SIZE 109 MB -> 5.59 GB, latency-bound G2). Keeps the 16-wave split.
//  - Grid barrier arrival is now a TWO-LEVEL TREE: 8 group counters (w&7,
//    256-B spaced lines, 32 wgs each) -> level-2 counter -> release flag.
//    r0/r1 serialized 256 same-line RMWs at the coherent point (~16 us/step).
//  - B2 barrier dropped: mask bytes are stored only by wave 0, and the
//    RELEASE fetch_add in the same wave drains vmcnt before the arrival.

// d_ws layout: [0,16384) mask buf0, [16384,32768) mask buf1,
//              [32768,+8*256) level-1 counters, [34816,+4) level-2 counter,
//              [35072,+4) release flag
#define WS_MASK0   0
#define WS_MASK1   16384
#define WS_CNT1    32768
#define WS_CNT2    34816
#define WS_FLAG    35072
#define WS_WORDS   8832    // zero through 35328 B (covers masks+counters+flag)
#define NGRP       8
#define GRPSZ      (NWG / NGRP)

struct SMem {
  float    WtT[SL][NRES];           // 65536 B : WtT[il][j] = W_res[8w+il][j]
  float    WinT2[SL][C_];           //  4096 B : W_in rows (staged once)
  float    xs[B_][C_ + 1];          // 33024 B : x[:, :, t], row-padded
  unsigned mask[B_][65];            // 16640 B : spike bits s(t-1), row-padded
  float    part[SL][B_][5];         // 10240 B : {a2, a3, g1} per (il, b), pad 5
  unsigned long long balls[SL];     //    64 B : per-wave spike ballots (half0)
  double   clfred[16][NCLS];        //  1280 B : classifier per-wave partials
};                                   // total ~130880 B => 1 wg/CU (grid = 256)

__global__ void zero_ws_kernel(unsigned* __restrict__ p, int n) {
  int i = blockIdx.x * blockDim.x + threadIdx.x;
  if (i < n) p[i] = 0u;
}

// ascending-j masked add into chain A; bfe(sign-extend bit) + and + fadd
#define ACC1(A, W, M, JB) \
  (A) = __fadd_rn((A), __uint_as_float((unsigned)(((int)((M) << (31 - (JB)))) >> 31) & __float_as_uint(W)))

__global__ void __launch_bounds__(NT, 4)
reservoir_kernel(const float* __restrict__ x, const float* __restrict__ Win,
                 const float* __restrict__ Wres, const float* __restrict__ Wclf,
                 float* __restrict__ out, unsigned char* __restrict__ ws) {
  __shared__ SMem sm;
  const int w     = blockIdx.x;
  const int tid   = threadIdx.x;
  const int b     = tid & 63;        // lane = batch
  const int wid   = tid >> 6;        // wave index 0..15
  const int il    = wid & 7;         // local neuron index
  const int halfb = wid >> 3;        // 0: blocks 0,1 + LIF ; 1: blocks 2,3 + G1
  const int iu    = __builtin_amdgcn_readfirstlane(w * SL + il);

  unsigned* mbuf0 = (unsigned*)(ws + WS_MASK0);
  unsigned* mbuf1 = (unsigned*)(ws + WS_MASK1);
  unsigned* cnt1  = (unsigned*)(ws + WS_CNT1 + (w & (NGRP - 1)) * 256);
  unsigned* cnt2  = (unsigned*)(ws + WS_CNT2);
  unsigned* flag  = (unsigned*)(ws + WS_FLAG);

  // ---- one-time: stage W_res half-rows (64 KB) + W_in rows (4 KB) to LDS ----
  {
    const float* wsrc = Wres + (size_t)iu * NRES + halfb * 1024;
    #pragma unroll 8
    for (int k = 0; k < 16; ++k)
      sm.WtT[il][halfb * 1024 + k * 64 + b] = wsrc[k * 64 + b];
    sm.WinT2[il][halfb * 64 + b] = Win[(size_t)iu * C_ + halfb * 64 + b];
  }

  // ---- one-time: cache this thread's 20 Wclf values in VGPRs ----
  float wcf[NCLS * 2];
  {
    const int j0 = tid * 2;
    #pragma unroll
    for (int c2 = 0; c2 < NCLS; ++c2)
      #pragma unroll
      for (int jj = 0; jj < 2; ++jj)
        wcf[c2 * 2 + jj] = Wclf[(size_t)c2 * NRES + j0 + jj];
  }

  // persistent state: EXACT replica of the np float32 trajectory
  float v = 0.f;                   // reservoir membrane (half0 threads only)
  int   cntr = 0;
  double vc = 0.0;                 // classifier membrane (no feedback -> f64 ok)
  int   cntc = 0;

  // prefetch x(:,:,0): flat pair p = tid*8 + r, p = b*C_ + c
  float xv[8];
  {
    const int p0 = tid * 8;
    #pragma unroll
    for (int r = 0; r < 8; ++r) xv[r] = x[(size_t)(p0 + r) * T_ + 0];
  }

  for (int t = 0; t < T_; ++t) {
    unsigned* prevm = (t & 1) ? mbuf0 : mbuf1;   // s(t-1); t=0 reads zeroed buf1
    unsigned char* curm = (unsigned char*)((t & 1) ? mbuf1 : mbuf0);

    // ---- stage prev spike masks (coherent atomic loads -> LDS) ----
    unsigned mm[4];
    {
      const int k0 = tid * 4;
      #pragma unroll
      for (int r = 0; r < 4; ++r)
        mm[r] = __hip_atomic_load(prevm + k0 + r, __ATOMIC_RELAXED,
                                  __HIP_MEMORY_SCOPE_AGENT);
    }
    // ---- xs <- xv (x for this step, staged from prefetch regs) ----
    {
      const int p0 = tid * 8;
      #pragma unroll
      for (int r = 0; r < 8; ++r) {
        int p = p0 + r;
        sm.xs[p >> 7][p & 127] = xv[r];
      }
    }
    {
      const int k0 = tid * 4;
      #pragma unroll
      for (int r = 0; r < 4; ++r) {
        int k = k0 + r;
        sm.mask[k >> 6][k & 63] = mm[r];
      }
    }
    __syncthreads();  // A: xs + mask ready (also guards one-time stages at t=0)

    // ---- prefetch next step's x ----
    if (t + 1 < T_) {
      const int p0 = tid * 8;
      #pragma unroll
      for (int r = 0; r < 8; ++r) xv[r] = x[(size_t)(p0 + r) * T_ + (t + 1)];
    }

    // ---- G1 (half1 only): feedforward, pure f32 fma chain c=0..127 ----
    float g1 = 0.f;
    if (halfb) {
      const float* winl = &sm.WinT2[il][0];
      #pragma unroll 16
      for (int c = 0; c < C_; ++c)
        g1 = fmaf(sm.xs[b][c], winl[c], g1);
    }

    // ---- G2 half: two independent KC=512 block chains, interleaved ----
    float aA = 0.f, aB = 0.f;
    {
      const float*    wrow = &sm.WtT[il][halfb * 1024];  // wave-uniform
      const unsigned* mrow = &sm.mask[b][0];
      const int mo = halfb * 32;
      for (int wq = 0; wq < 16; ++wq) {
        unsigned mwA = mrow[mo + wq];
        unsigned mwB = mrow[mo + 16 + wq];
        const float4* q0 = (const float4*)(wrow + wq * 32);
        const float4* q1 = (const float4*)(wrow + 512 + wq * 32);
        #pragma unroll
        for (int jq = 0; jq < 8; ++jq) {
          const float4 wA = q0[jq];
          const float4 wB = q1[jq];
          const int jb = jq * 4;
          ACC1(aA, wA.x, mwA, jb + 0); ACC1(aA, wA.y, mwA, jb + 1);
          ACC1(aA, wA.z, mwA, jb + 2); ACC1(aA, wA.w, mwA, jb + 3);
          ACC1(aB, wB.x, mwB, jb + 0); ACC1(aB, wB.y, mwB, jb + 1);
          ACC1(aB, wB.z, mwB, jb + 2); ACC1(aB, wB.w, mwB, jb + 3);
        }
      }
    }

    // ---- half1 publishes partials {a2, a3, g1} ----
    if (halfb) {
      sm.part[il][b][0] = aA;
      sm.part[il][b][1] = aB;
      sm.part[il][b][2] = g1;
    }
    __syncthreads();  // E: partials ready

    // ---- half0: exact fold + LIF update + ballot ----
    if (!halfb) {
      const float a2  = sm.part[il][b][0];
      const float a3  = sm.part[il][b][1];
      const float g1p = sm.part[il][b][2];
      // fold order identical to r10-r12: ((blk0 + blk1) + blk2) + blk3
      float g2 = __fadd_rn(__fadd_rn(__fadd_rn(aA, aB), a2), a3);
      float I  = __fadd_rn(g1p, g2);
      v = __fadd_rn(__fmul_rn(0.9f, v), I);
      bool s = (v >= 1.0f);
      if (s) { v = 0.f; cntr++; }
      unsigned long long bal = __ballot(s);  // bit b = spike(batch b, neuron iu)
      if (b == 0) sm.balls[il] = bal;
    }
    __syncthreads();  // B: balls ready

    // ---- wave 0: assemble + store spike bytes, then TREE ARRIVAL ----
    // (mask stores are only by this wave; the RELEASE fetch_add drains them)
    if (tid < B_) {
      unsigned byte = 0;
      #pragma unroll
      for (int il2 = 0; il2 < SL; ++il2)
        byte |= ((unsigned)((sm.balls[il2] >> tid) & 1ull)) << il2;
      __hip_atomic_store(curm + tid * 256 + w, (unsigned char)byte,
                         __ATOMIC_RELAXED, __HIP_MEMORY_SCOPE_AGENT);
      if (tid == 0) {
        unsigned old = __hip_atomic_fetch_add(cnt1, 1u, __ATOMIC_RELEASE,
                                              __HIP_MEMORY_SCOPE_AGENT);
        if (old == (unsigned)(t + 1) * GRPSZ - 1u) {
          unsigned old2 = __hip_atomic_fetch_add(cnt2, 1u, __ATOMIC_ACQ_REL,
                                                 __HIP_MEMORY_SCOPE_AGENT);
          if (old2 == (unsigned)(t + 1) * NGRP - 1u)
            __hip_atomic_store(flag, (unsigned)(t + 1), __ATOMIC_RELEASE,
                               __HIP_MEMORY_SCOPE_AGENT);
        }
      }
    }

    // ---- classifier partials for s(t-1) DURING the poll window (wg<64) ----
    if (w < B_) {
      double pc[NCLS];
      #pragma unroll
      for (int c2 = 0; c2 < NCLS; ++c2) pc[c2] = 0.0;
      if (t > 0) {
        const int j0 = tid * 2;
        unsigned mw = sm.mask[w][j0 >> 5];
        #pragma unroll
        for (int jj = 0; jj < 2; ++jj) {
          if ((mw >> ((j0 + jj) & 31)) & 1u) {
            #pragma unroll
            for (int c2 = 0; c2 < NCLS; ++c2)
              pc[c2] += (double)wcf[c2 * 2 + jj];
          }
        }
      }
      #pragma unroll
      for (int off = 1; off < 64; off <<= 1) {
        #pragma unroll
        for (int c2 = 0; c2 < NCLS; ++c2)
          pc[c2] += __shfl_xor(pc[c2], off, 64);
      }
      if ((tid & 63) == 0) {
        int wv = tid >> 6;
        #pragma unroll
        for (int c2 = 0; c2 < NCLS; ++c2) sm.clfred[wv][c2] = pc[c2];
      }
    }
    __syncthreads();  // C: clfred ready

    // ---- classifier LIF update (wg<64, tid<10) ----
    if (w < B_ && tid < NCLS) {
      double sc = 0.0;
      #pragma unroll
      for (int q2 = 0; q2 < 16; ++q2) sc += sm.clfred[q2][tid];
      vc = 0.9 * vc + sc;
      if (vc >= 1.0) { vc = 0.0; cntc++; }
    }

    // ---- poll the release flag (read-shared line, no RMW interference) ----
    if (tid == 0) {
      while (__hip_atomic_load(flag, __ATOMIC_RELAXED,
                               __HIP_MEMORY_SCOPE_AGENT) < (unsigned)(t + 1))
        __builtin_amdgcn_s_sleep(1);
    }
    __syncthreads();  // D: whole wg proceeds past the grid barrier
  }

  // ---- epilogue: classifier step for s(T-1) (in buf1 since 499&1==1) ----
  if (w < B_ && tid < 64)
    sm.mask[w][tid] = __hip_atomic_load(mbuf1 + w * 64 + tid, __ATOMIC_RELAXED,
                                        __HIP_MEMORY_SCOPE_AGENT);
  __syncthreads();
  if (w < B_) {
    double pc[NCLS];
    #pragma unroll
    for (int c2 = 0; c2 < NCLS; ++c2) pc[c2] = 0.0;
    const int j0 = tid * 2;
    unsigned mw = sm.mask[w][j0 >> 5];
    #pragma unroll
    for (int jj = 0; jj < 2; ++jj) {
      if ((mw >> ((j0 + jj) & 31)) & 1u) {
        #pragma unroll
        for (int c2 = 0; c2 < NCLS; ++c2)
          pc[c2] += (double)wcf[c2 * 2 + jj];
      }
    }
    #pragma unroll
    for (int off = 1; off < 64; off <<= 1) {
      #pragma unroll
      for (int c2 = 0; c2 < NCLS; ++c2)
        pc[c2] += __shfl_xor(pc[c2], off, 64);
    }
    if ((tid & 63) == 0) {
      int wv = tid >> 6;
      #pragma unroll
      for (int c2 = 0; c2 < NCLS; ++c2) sm.clfred[wv][c2] = pc[c2];
    }
  }
  __syncthreads();
  if (w < B_ && tid < NCLS) {
    double sc = 0.0;
    #pragma unroll
    for (int q2 = 0; q2 < 16; ++q2) sc += sm.clfred[q2][tid];
    vc = 0.9 * vc + sc;
    if (vc >= 1.0) cntc++;
    out[w * NCLS + tid] = (float)cntc;
  }
  // ---- reservoir spike counts: half0 thread (b, il) owns (b, iu) ----
  if (halfb == 0)
    out[B_ * NCLS + (size_t)b * NRES + w * SL + il] = (float)cntr;
}

extern "C" void kernel_launch(void* const* d_in, const int* in_sizes, int n_in,
                              void* d_out, int out_size, void* d_ws, size_t ws_size,
                              hipStream_t stream) {
  const float* x    = (const float*)d_in[0];   // (B, C, T)
  const float* Win  = (const float*)d_in[1];   // (NRES, C)
  const float* Wres = (const float*)d_in[2];   // (NRES, NRES)
  const float* Wclf = (const float*)d_in[3];   // (NCLS, NRES)
  float* out = (float*)d_out;
  unsigned char* ws = (unsigned char*)d_ws;

  hipLaunchKernelGGL(zero_ws_kernel, dim3((WS_WORDS + 255) / 256), dim3(256), 0, stream,
                     (unsigned*)ws, WS_WORDS);
  hipLaunchKernelGGL(reservoir_kernel, dim3(NWG), dim3(NT), 0, stream,
                     x, Win, Wres, Wclf, out, ws);
}

// Round 3
// 17292.554 us; speedup vs baseline: 1.3750x; 1.0438x over previous
//
#include <hip/hip_runtime.h>
#include <cstdint>
#include <cstddef>

// Problem constants (match reference)
#define B_    64
#define C_    128
#define T_    500
#define NRES  2048
#define NCLS  10

// Kernel org: 256 wgs (one per CU), 1024 threads = 16 waves.
// wid = tid>>6 ; il = wid&7 (neuron) ; h = wid>>3 (batch half).
// G2 TRANSPOSED assignment: lane l of wave (il,h): blk = l&3, g = l>>2;
// owns block blk of batches bat0 = h*32+2g, bat1 = bat0+1 (two 512-chains).
// One ds_read_b128 now feeds 4 distinct blocks x 16-lane broadcast groups
// -> weight-feed LDS instructions halve (4096 -> 2048 per CU per step).
// Block rows skewed +8 words (pitch 520) => the 4 concurrent addresses hit
// disjoint bank quads (conflict-free).
#define NWG   256
#define SL    8
#define NT    1024
#define WROW  520              // skewed words per 512-block row
#define WPIT  (4 * WROW)       // words per neuron row in LDS

// BIT-EXACT MODEL (validated r10-r12 + split rounds, absmax 0.0):
// G1: ascending fmaf chain (K=128, one block). G2: KC=512 blocks
// [512,512,512,512], each an ascending masked rn-add chain starting at 0,
// folded left-to-right ((b0+b1)+b2)+b3. LIF: v = rn(rn(0.9f*v) + rn(g1+g2)).
// DO NOT CHANGE THE ARITHMETIC. Transpose keeps each 512-chain sequential in
// one lane (ascending j), fold order exact via shfl gathers in blk0 lane.

// d_ws layout: [0,16384) mask buf0, [16384,32768) mask buf1,
//              [32768,+8*256) level-1 counters, [34816,+4) level-2 counter,
//              [35072,+4) release flag
#define WS_MASK0   0
#define WS_MASK1   16384
#define WS_CNT1    32768
#define WS_CNT2    34816
#define WS_FLAG    35072
#define WS_WORDS   8832
#define NGRP       8
#define GRPSZ      (NWG / NGRP)

struct SMem {
  float    WtT2[SL][WPIT];          // 66560 B : skewed W_res rows
  float    WinT2[SL][C_];           //  4096 B : W_in rows
  float    xs[B_][C_ + 1];          // 33024 B : x[:, :, t], row-padded
  unsigned mask[B_][65];            // 16640 B : spike bits s(t-1), row-padded
  float    g1buf[SL][B_];           //  2048 B : G1 results (il, bat)
  unsigned balls2[SL][2];           //    64 B : per-(il,h) 32-bit spike masks
  double   clfred[16][NCLS];        //  1280 B : classifier per-wave partials
};                                   // total 123712 B => 1 wg/CU (grid = 256)

__global__ void zero_ws_kernel(unsigned* __restrict__ p, int n) {
  int i = blockIdx.x * blockDim.x + threadIdx.x;
  if (i < n) p[i] = 0u;
}

// ascending-j masked add into chain A; bfe(sign-extend bit) + and + fadd
#define ACC1(A, W, M, JB) \
  (A) = __fadd_rn((A), __uint_as_float((unsigned)(((int)((M) << (31 - (JB)))) >> 31) & __float_as_uint(W)))

__global__ void __launch_bounds__(NT, 4)
reservoir_kernel(const float* __restrict__ x, const float* __restrict__ Win,
                 const float* __restrict__ Wres, const float* __restrict__ Wclf,
                 float* __restrict__ out, unsigned char* __restrict__ ws) {
  __shared__ SMem sm;
  const int w   = blockIdx.x;
  const int tid = threadIdx.x;
  const int b   = tid & 63;          // lane index
  const int wid = tid >> 6;          // wave index 0..15
  const int il  = wid & 7;           // neuron within wg
  const int h   = wid >> 3;          // batch half (0: bats 0-31, 1: 32-63)
  const int blk = b & 3;             // G2: block owned by this lane
  const int g   = b >> 2;            // G2: batch pair group
  const int bat0 = h * 32 + g * 2;   // G2: even batch
  const int bat1 = bat0 + 1;         // G2: odd batch

  unsigned* mbuf0 = (unsigned*)(ws + WS_MASK0);
  unsigned* mbuf1 = (unsigned*)(ws + WS_MASK1);
  unsigned* cnt1  = (unsigned*)(ws + WS_CNT1 + (w & (NGRP - 1)) * 256);
  unsigned* cnt2  = (unsigned*)(ws + WS_CNT2);
  unsigned* flag  = (unsigned*)(ws + WS_FLAG);

  // ---- one-time: stage skewed W_res rows (16 float4 per thread) ----
  {
    const int j0 = tid * 16;                   // 16384 weights total
    #pragma unroll
    for (int r4 = 0; r4 < 4; ++r4) {
      const int j   = j0 + r4 * 4;             // multiple of 4, within one blk
      const int il2 = j >> 11;
      const int pos = j & 2047;
      const int bk  = pos >> 9;
      const int s   = pos & 511;
      const float4 v4 = *(const float4*)(Wres + (size_t)(w * SL + il2) * NRES + pos);
      *(float4*)(&sm.WtT2[il2][bk * WROW + s]) = v4;
    }
  }
  // ---- one-time: stage W_in rows (1 element per thread) ----
  {
    const int il2 = tid >> 7, c = tid & 127;
    sm.WinT2[il2][c] = Win[(size_t)(w * SL + il2) * C_ + c];
  }

  // ---- one-time: cache this thread's 20 Wclf values in VGPRs ----
  float wcf[NCLS * 2];
  {
    const int j0 = tid * 2;
    #pragma unroll
    for (int c2 = 0; c2 < NCLS; ++c2)
      #pragma unroll
      for (int jj = 0; jj < 2; ++jj)
        wcf[c2 * 2 + jj] = Wclf[(size_t)c2 * NRES + j0 + jj];
  }

  // persistent state (lanes b<32 hold v for bat = h*32 + b)
  float v = 0.f;
  int   cntr = 0;
  double vc = 0.0;
  int   cntc = 0;

  // prefetch x(:,:,0) and stage xs(0)
  float xv[8];
  {
    const int p0 = tid * 8;
    #pragma unroll
    for (int r = 0; r < 8; ++r) xv[r] = x[(size_t)(p0 + r) * T_ + 0];
    #pragma unroll
    for (int r = 0; r < 8; ++r) {
      int p = p0 + r;
      sm.xs[p >> 7][p & 127] = xv[r];
    }
  }

  for (int t = 0; t < T_; ++t) {
    unsigned* prevm = (t & 1) ? mbuf0 : mbuf1;   // s(t-1); t=0 reads zeroed buf1
    unsigned char* curm = (unsigned char*)((t & 1) ? mbuf1 : mbuf0);

    // ---- stage prev spike masks (coherent atomic loads -> LDS) ----
    {
      unsigned mm[4];
      const int k0 = tid * 4;
      #pragma unroll
      for (int r = 0; r < 4; ++r)
        mm[r] = __hip_atomic_load(prevm + k0 + r, __ATOMIC_RELAXED,
                                  __HIP_MEMORY_SCOPE_AGENT);
      #pragma unroll
      for (int r = 0; r < 4; ++r) {
        int k = k0 + r;
        sm.mask[k >> 6][k & 63] = mm[r];
      }
    }
    __syncthreads();  // A: mask ready (xs staged at prev iter bottom / prologue)

    // ---- prefetch next step's x ----
    if (t + 1 < T_) {
      const int p0 = tid * 8;
      #pragma unroll
      for (int r = 0; r < 8; ++r) xv[r] = x[(size_t)(p0 + r) * T_ + (t + 1)];
    }

    // ---- G1 (waves 0..7: il=wid, lane=bat): ascending fmaf chain ----
    if (h == 0) {
      float g1 = 0.f;
      const float4* __restrict__ winp = (const float4*)&sm.WinT2[il][0];
      #pragma unroll 8
      for (int cq = 0; cq < 32; ++cq) {
        const float4 wv = winp[cq];
        const int c = cq * 4;
        g1 = fmaf(sm.xs[b][c + 0], wv.x, g1);
        g1 = fmaf(sm.xs[b][c + 1], wv.y, g1);
        g1 = fmaf(sm.xs[b][c + 2], wv.z, g1);
        g1 = fmaf(sm.xs[b][c + 3], wv.w, g1);
      }
      sm.g1buf[il][b] = g1;
    }

    // ---- G2 transposed: lane (blk,g) runs block blk for bat0,bat1 ----
    float aP = 0.f, aQ = 0.f;       // block partials for bat0 / bat1
    {
      const float*    wbase = &sm.WtT2[il][blk * WROW];  // per-lane blk addr
      const unsigned* mr0   = &sm.mask[bat0][blk * 16];
      const unsigned* mr1   = &sm.mask[bat1][blk * 16];
      for (int wq = 0; wq < 16; ++wq) {
        const unsigned m0 = mr0[wq];
        const unsigned m1 = mr1[wq];
        const float4* q = (const float4*)(wbase + wq * 32);
        #pragma unroll
        for (int jq = 0; jq < 8; ++jq) {
          const float4 w4 = q[jq];
          const int jb = jq * 4;
          ACC1(aP, w4.x, m0, jb + 0); ACC1(aP, w4.y, m0, jb + 1);
          ACC1(aP, w4.z, m0, jb + 2); ACC1(aP, w4.w, m0, jb + 3);
          ACC1(aQ, w4.x, m1, jb + 0); ACC1(aQ, w4.y, m1, jb + 1);
          ACC1(aQ, w4.z, m1, jb + 2); ACC1(aQ, w4.w, m1, jb + 3);
        }
      }
    }

    // ---- intra-wave fold to blk0 lanes: ((b0+b1)+b2)+b3 exact order ----
    const float p1 = __shfl_xor(aP, 1), q1 = __shfl_xor(aQ, 1);
    const float p2 = __shfl_xor(aP, 2), q2 = __shfl_xor(aQ, 2);
    const float p3 = __shfl_xor(aP, 3), q3 = __shfl_xor(aQ, 3);
    const float g2u0 = __fadd_rn(__fadd_rn(__fadd_rn(aP, p1), p2), p3);
    const float g2u1 = __fadd_rn(__fadd_rn(__fadd_rn(aQ, q1), q2), q3);

    __syncthreads();  // X: g1buf ready (and all G2/fold done)

    // ---- redistribute to lane=bat (b<32), read g1, LIF update ----
    {
      const int src = (b >> 1) * 4;            // blk0 lane of my batch pair
      const float r0 = __shfl(g2u0, src, 64);
      const float r1 = __shfl(g2u1, src, 64);
      const float g2m = (b & 1) ? r1 : r0;
      const float g1m = sm.g1buf[il][h * 32 + (b & 31)];
      const float I = __fadd_rn(g1m, g2m);
      v = __fadd_rn(__fmul_rn(0.9f, v), I);
      bool s = (b < 32) && (v >= 1.0f);
      if (s) { v = 0.f; cntr++; }
      unsigned long long bal = __ballot(s);    // bits 0..31 = bats h*32..+31
      if (b == 0) sm.balls2[il][h] = (unsigned)bal;
    }
    __syncthreads();  // B: balls2 ready

    // ---- wave 0: assemble + store spike bytes, then TREE ARRIVAL ----
    if (tid < B_) {
      const int hh = tid >> 5, mb = tid & 31;
      unsigned byte = 0;
      #pragma unroll
      for (int il2 = 0; il2 < SL; ++il2)
        byte |= ((sm.balls2[il2][hh] >> mb) & 1u) << il2;
      __hip_atomic_store(curm + tid * 256 + w, (unsigned char)byte,
                         __ATOMIC_RELAXED, __HIP_MEMORY_SCOPE_AGENT);
      if (tid == 0) {
        unsigned old = __hip_atomic_fetch_add(cnt1, 1u, __ATOMIC_RELEASE,
                                              __HIP_MEMORY_SCOPE_AGENT);
        if (old == (unsigned)(t + 1) * GRPSZ - 1u) {
          unsigned old2 = __hip_atomic_fetch_add(cnt2, 1u, __ATOMIC_ACQ_REL,
                                                 __HIP_MEMORY_SCOPE_AGENT);
          if (old2 == (unsigned)(t + 1) * NGRP - 1u)
            __hip_atomic_store(flag, (unsigned)(t + 1), __ATOMIC_RELEASE,
                               __HIP_MEMORY_SCOPE_AGENT);
        }
      }
    }

    // ---- classifier partials for s(t-1) DURING the poll window (wg<64) ----
    if (w < B_) {
      double pc[NCLS];
      #pragma unroll
      for (int c2 = 0; c2 < NCLS; ++c2) pc[c2] = 0.0;
      if (t > 0) {
        const int j0 = tid * 2;
        unsigned mw = sm.mask[w][j0 >> 5];
        #pragma unroll
        for (int jj = 0; jj < 2; ++jj) {
          if ((mw >> ((j0 + jj) & 31)) & 1u) {
            #pragma unroll
            for (int c2 = 0; c2 < NCLS; ++c2)
              pc[c2] += (double)wcf[c2 * 2 + jj];
          }
        }
      }
      #pragma unroll
      for (int off = 1; off < 64; off <<= 1) {
        #pragma unroll
        for (int c2 = 0; c2 < NCLS; ++c2)
          pc[c2] += __shfl_xor(pc[c2], off, 64);
      }
      if ((tid & 63) == 0) {
        #pragma unroll
        for (int c2 = 0; c2 < NCLS; ++c2) sm.clfred[wid][c2] = pc[c2];
      }
    }
    __syncthreads();  // C: clfred ready

    // ---- classifier LIF update (wg<64, tid<10) ----
    if (w < B_ && tid < NCLS) {
      double sc = 0.0;
      #pragma unroll
      for (int q2 = 0; q2 < 16; ++q2) sc += sm.clfred[q2][tid];
      vc = 0.9 * vc + sc;
      if (vc >= 1.0) { vc = 0.0; cntc++; }
    }

    // ---- stage xs(t+1) during the poll window (reads ordered by D) ----
    if (t + 1 < T_) {
      const int p0 = tid * 8;
      #pragma unroll
      for (int r = 0; r < 8; ++r) {
        int p = p0 + r;
        sm.xs[p >> 7][p & 127] = xv[r];
      }
    }

    // ---- poll the release flag ----
    if (tid == 0) {
      while (__hip_atomic_load(flag, __ATOMIC_RELAXED,
                               __HIP_MEMORY_SCOPE_AGENT) < (unsigned)(t + 1))
        __builtin_amdgcn_s_sleep(1);
    }
    __syncthreads();  // D: whole wg proceeds past the grid barrier
  }

  // ---- epilogue: classifier step for s(T-1) (in buf1 since 499&1==1) ----
  if (w < B_ && tid < 64)
    sm.mask[w][tid] = __hip_atomic_load(mbuf1 + w * 64 + tid, __ATOMIC_RELAXED,
                                        __HIP_MEMORY_SCOPE_AGENT);
  __syncthreads();
  if (w < B_) {
    double pc[NCLS];
    #pragma unroll
    for (int c2 = 0; c2 < NCLS; ++c2) pc[c2] = 0.0;
    const int j0 = tid * 2;
    unsigned mw = sm.mask[w][j0 >> 5];
    #pragma unroll
    for (int jj = 0; jj < 2; ++jj) {
      if ((mw >> ((j0 + jj) & 31)) & 1u) {
        #pragma unroll
        for (int c2 = 0; c2 < NCLS; ++c2)
          pc[c2] += (double)wcf[c2 * 2 + jj];
      }
    }
    #pragma unroll
    for (int off = 1; off < 64; off <<= 1) {
      #pragma unroll
      for (int c2 = 0; c2 < NCLS; ++c2)
        pc[c2] += __shfl_xor(pc[c2], off, 64);
    }
    if ((tid & 63) == 0) {
      #pragma unroll
      for (int c2 = 0; c2 < NCLS; ++c2) sm.clfred[wid][c2] = pc[c2];
    }
  }
  __syncthreads();
  if (w < B_ && tid < NCLS) {
    double sc = 0.0;
    #pragma unroll
    for (int q2 = 0; q2 < 16; ++q2) sc += sm.clfred[q2][tid];
    vc = 0.9 * vc + sc;
    if (vc >= 1.0) cntc++;
    out[w * NCLS + tid] = (float)cntc;
  }
  // ---- reservoir spike counts: lane b<32 of wave (il,h) owns (h*32+b, iu) ----
  if (b < 32)
    out[B_ * NCLS + (size_t)(h * 32 + b) * NRES + w * SL + il] = (float)cntr;
}

extern "C" void kernel_launch(void* const* d_in, const int* in_sizes, int n_in,
                              void* d_out, int out_size, void* d_ws, size_t ws_size,
                              hipStream_t stream) {
  const float* x    = (const float*)d_in[0];   // (B, C, T)
  const float* Win  = (const float*)d_in[1];   // (NRES, C)
  const float* Wres = (const float*)d_in[2];   // (NRES, NRES)
  const float* Wclf = (const float*)d_in[3];   // (NCLS, NRES)
  float* out = (float*)d_out;
  unsigned char* ws = (unsigned char*)d_ws;

  hipLaunchKernelGGL(zero_ws_kernel, dim3((WS_WORDS + 255) / 256), dim3(256), 0, stream,
                     (unsigned*)ws, WS_WORDS);
  hipLaunchKernelGGL(reservoir_kernel, dim3(NWG), dim3(NT), 0, stream,
                     x, Win, Wres, Wclf, out, ws);
}

// Round 5
// 15907.239 us; speedup vs baseline: 1.4948x; 1.0871x over previous
//
#include <hip/hip_runtime.h>
#include <cstdint>
#include <cstddef>

// Problem constants (match reference)
#define B_    64
#define C_    128
#define T_    500
#define NRES  2048
#define NCLS  10

// Kernel org: 256 wgs (one per CU), 1024 threads = 16 waves.
// wid = tid>>6 ; il = wid&7 (neuron) ; h = wid>>3 (batch half).
// G2 transposed: lane l of wave (il,h): blk = l&3, g = l>>2; owns block blk
// of batches bat0 = h*32+2g, bat1 = bat0+1. bat0/bat1 chains packed in one
// v2f accumulator (element-wise IEEE RN adds — bit-exact per chain).
#define NWG   256
#define SL    8
#define NT    1024
#define WROW  520              // skewed words per 512-block row
#define WPIT  (4 * WROW)       // words per neuron row in LDS

// BIT-EXACT MODEL (validated, absmax 0.0): G1: ascending fmaf chain (K=128).
// G2: KC=512 blocks [512,512,512,512], each an ascending masked rn-add chain
// starting at 0, folded left-to-right ((b0+b1)+b2)+b3.
// LIF: v = rn(rn(0.9f*v) + rn(g1+g2)). DO NOT CHANGE THE ARITHMETIC.

// r4/r5 communication redesign (r3 counters: WRITE_SIZE 529 KB/step of HBM
// writeback for 16 KB of mask payload -> ~8K line-RMWs/step from 64-byte
// scatters x 256 wgs into the same 64 lines; 256 pollers on one flag line):
//  - NEURON-MAJOR mask format: gm[j*2+h] = 32-bit ballot (bats h*32..+31,
//    neuron j). Writer wg stores 16 contiguous dwords = ONE 64-B line.
//  - Readers rebuild bat-major rows via in-wave 32x32 bit transposes
//    (shfl_xor ladder, deltas 16/8/4/2/1 — both 32-lane halves in parallel).
//  - 16 release flags spread 1 KB apart (different TCC channels); wg polls
//    flag[w&15] -> 16 pollers/line.
//  - clfred double-buffered: classifier LIF consumes prev step's partials
//    (barrier C removed; two deferred consumes in the epilogue).

// d_ws layout
#define WS_MASK0   0            // 16 KB: gm buf0 (4096 words: j*2+h)
#define WS_MASK1   16384        // 16 KB: gm buf1
#define WS_CNT1    32768        // 8 x 256 B level-1 counters
#define WS_CNT2    34816        // level-2 counter
#define WS_FLAG    36864        // 16 flags, 1024 B apart
#define WS_WORDS   13312        // zero through 53248 B
#define NGRP       8
#define GRPSZ      (NWG / NGRP)
#define NFLAG      16

typedef float v2f __attribute__((ext_vector_type(2)));

struct SMem {
  float    WtT2[SL][WPIT];          // 66560 B : skewed W_res rows
  float    WinT2[SL][C_];           //  4096 B : W_in rows
  float    xs[B_][C_ + 1];          // 33024 B : x[:, :, t], row-padded
  unsigned mask[B_][65];            // 16640 B : bat-major spike words s(t-1)
  float    g1buf[SL][B_];           //  2048 B : G1 results (il, bat)
  double   clfred[2][16][NCLS];     //  2560 B : classifier partials, 2 bufs
};                                   // total 124928 B => 1 wg/CU (grid = 256)

__global__ void zero_ws_kernel(unsigned* __restrict__ p, int n) {
  int i = blockIdx.x * blockDim.x + threadIdx.x;
  if (i < n) p[i] = 0u;
}

// packed masked add: lanes' bat0/bat1 chains advance together.
// bfe(sign-extend bit)x2 + and x2 + <2 x float> fadd (RN per elem, bit-exact).
#define ACC2(ACC, WB, M0, M1, JB) do {                                        \
  const unsigned _lo = (unsigned)(((int)((M0) << (31 - (JB)))) >> 31) & (WB); \
  const unsigned _hi = (unsigned)(((int)((M1) << (31 - (JB)))) >> 31) & (WB); \
  v2f _m; _m.x = __uint_as_float(_lo); _m.y = __uint_as_float(_hi);           \
  (ACC) = (ACC) + _m;                                                         \
} while (0)

// one step of the 32x32 bit-matrix transpose ladder (periodic masks):
// element view: A'[r][c] = (r&D)==(c&D) ? A[r][c] : A[r^D][c^D]
#define BT_STEP(X, D, MLO) do {                                            \
  const unsigned _y = (unsigned)__shfl_xor((int)(X), (D), 64);             \
  (X) = (b & (D)) ? (((X) & ~(MLO)) | ((_y >> (D)) & (MLO)))               \
                  : (((X) & (MLO)) | ((_y << (D)) & ~(MLO)));              \
} while (0)

#define BT_ALL(X) do {                 \
  BT_STEP(X, 16, 0x0000FFFFu);         \
  BT_STEP(X,  8, 0x00FF00FFu);         \
  BT_STEP(X,  4, 0x0F0F0F0Fu);         \
  BT_STEP(X,  2, 0x33333333u);         \
  BT_STEP(X,  1, 0x55555555u);         \
} while (0)

__global__ void __launch_bounds__(NT, 4)
reservoir_kernel(const float* __restrict__ x, const float* __restrict__ Win,
                 const float* __restrict__ Wres, const float* __restrict__ Wclf,
                 float* __restrict__ out, unsigned char* __restrict__ ws) {
  __shared__ SMem sm;
  const int w   = blockIdx.x;
  const int tid = threadIdx.x;
  const int b   = tid & 63;          // lane index
  const int wid = tid >> 6;          // wave index 0..15
  const int il  = wid & 7;           // neuron within wg
  const int h   = wid >> 3;          // batch half
  const int blk = b & 3;             // G2: block owned by this lane
  const int g   = b >> 2;            // G2: batch pair group
  const int bat0 = h * 32 + g * 2;
  const int bat1 = bat0 + 1;
  const int iu  = __builtin_amdgcn_readfirstlane(w * SL + il);

  unsigned* gm0  = (unsigned*)(ws + WS_MASK0);
  unsigned* gm1  = (unsigned*)(ws + WS_MASK1);
  unsigned* cnt1 = (unsigned*)(ws + WS_CNT1 + (w & (NGRP - 1)) * 256);
  unsigned* cnt2 = (unsigned*)(ws + WS_CNT2);
  unsigned* flgb = (unsigned*)(ws + WS_FLAG);
  unsigned* myflag = flgb + (w & (NFLAG - 1)) * 256;   // 1024-B spacing

  // ---- one-time: stage skewed W_res rows (16 float4 per thread) ----
  {
    const int j0 = tid * 16;
    #pragma unroll
    for (int r4 = 0; r4 < 4; ++r4) {
      const int j   = j0 + r4 * 4;
      const int il2 = j >> 11;
      const int pos = j & 2047;
      const int bk  = pos >> 9;
      const int s   = pos & 511;
      const float4 v4 = *(const float4*)(Wres + (size_t)(w * SL + il2) * NRES + pos);
      *(float4*)(&sm.WtT2[il2][bk * WROW + s]) = v4;
    }
  }
  {
    const int il2 = tid >> 7, c = tid & 127;
    sm.WinT2[il2][c] = Win[(size_t)(w * SL + il2) * C_ + c];
  }

  // ---- one-time: cache this thread's 20 Wclf values in VGPRs ----
  float wcf[NCLS * 2];
  {
    const int j0 = tid * 2;
    #pragma unroll
    for (int c2 = 0; c2 < NCLS; ++c2)
      #pragma unroll
      for (int jj = 0; jj < 2; ++jj)
        wcf[c2 * 2 + jj] = Wclf[(size_t)c2 * NRES + j0 + jj];
  }

  float v = 0.f;
  int   cntr = 0;
  double vc = 0.0;
  int   cntc = 0;

  // prefetch x(:,:,0) and stage xs(0)
  float xv[8];
  {
    const int p0 = tid * 8;
    #pragma unroll
    for (int r = 0; r < 8; ++r) xv[r] = x[(size_t)(p0 + r) * T_ + 0];
    #pragma unroll
    for (int r = 0; r < 8; ++r) {
      int p = p0 + r;
      sm.xs[p >> 7][p & 127] = xv[r];
    }
  }

  for (int t = 0; t < T_; ++t) {
    unsigned* gprev = (t & 1) ? gm0 : gm1;   // s(t-1); t=0 reads zeroed gm1
    unsigned* gcur  = (t & 1) ? gm1 : gm0;

    // ---- load neuron-major ballots + 64x64 bit transpose -> sm.mask ----
    // wave wid owns word-columns k = wid*4..+3; lane (hh=b>>5, i=b&31) holds
    // gm[(32k+i)*2+hh]: bit bat' = s[hh*32+bat'][32k+i]. Each 32-lane half
    // transposes its 32x32 block via the shfl ladder; afterwards lane
    // (hh,i) = batch hh*32+i holds bits j' = s[bat][32k+j'] -> sm.mask[b][k].
    {
      const int i32 = b & 31, hh = b >> 5;
      #pragma unroll
      for (int kk = 0; kk < 4; ++kk) {
        const int k = (wid << 2) | kk;
        unsigned xw = __hip_atomic_load(gprev + (k * 32 + i32) * 2 + hh,
                                        __ATOMIC_RELAXED, __HIP_MEMORY_SCOPE_AGENT);
        BT_ALL(xw);
        sm.mask[b][k] = xw;
      }
    }
    __syncthreads();  // A: mask + xs ready (also guards one-time stages at t=0)

    // ---- prefetch next step's x ----
    if (t + 1 < T_) {
      const int p0 = tid * 8;
      #pragma unroll
      for (int r = 0; r < 8; ++r) xv[r] = x[(size_t)(p0 + r) * T_ + (t + 1)];
    }

    // ---- G1 (waves 0..7: il=wid, lane=bat): ascending fmaf chain ----
    if (h == 0) {
      float g1 = 0.f;
      const float4* __restrict__ winp = (const float4*)&sm.WinT2[il][0];
      #pragma unroll 8
      for (int cq = 0; cq < 32; ++cq) {
        const float4 wv = winp[cq];
        const int c = cq * 4;
        g1 = fmaf(sm.xs[b][c + 0], wv.x, g1);
        g1 = fmaf(sm.xs[b][c + 1], wv.y, g1);
        g1 = fmaf(sm.xs[b][c + 2], wv.z, g1);
        g1 = fmaf(sm.xs[b][c + 3], wv.w, g1);
      }
      sm.g1buf[il][b] = g1;
    }

    // ---- G2 transposed + packed: block blk of bat0 (lo) and bat1 (hi) ----
    v2f acc; acc.x = 0.f; acc.y = 0.f;
    {
      const float*    wbase = &sm.WtT2[il][blk * WROW];
      const unsigned* mr0   = &sm.mask[bat0][blk * 16];
      const unsigned* mr1   = &sm.mask[bat1][blk * 16];
      for (int wq = 0; wq < 16; ++wq) {
        const unsigned m0 = mr0[wq];
        const unsigned m1 = mr1[wq];
        const float4* q = (const float4*)(wbase + wq * 32);
        #pragma unroll
        for (int jq = 0; jq < 8; ++jq) {
          const float4 w4 = q[jq];
          const int jb = jq * 4;
          ACC2(acc, __float_as_uint(w4.x), m0, m1, jb + 0);
          ACC2(acc, __float_as_uint(w4.y), m0, m1, jb + 1);
          ACC2(acc, __float_as_uint(w4.z), m0, m1, jb + 2);
          ACC2(acc, __float_as_uint(w4.w), m0, m1, jb + 3);
        }
      }
    }
    const float aP = acc.x, aQ = acc.y;

    // ---- intra-wave fold to blk0 lanes: ((b0+b1)+b2)+b3 exact order ----
    const float p1 = __shfl_xor(aP, 1), q1 = __shfl_xor(aQ, 1);
    const float p2 = __shfl_xor(aP, 2), q2 = __shfl_xor(aQ, 2);
    const float p3 = __shfl_xor(aP, 3), q3 = __shfl_xor(aQ, 3);
    const float g2u0 = __fadd_rn(__fadd_rn(__fadd_rn(aP, p1), p2), p3);
    const float g2u1 = __fadd_rn(__fadd_rn(__fadd_rn(aQ, q1), q2), q3);

    __syncthreads();  // X: g1buf ready

    // ---- redistribute to lane=bat (b<32), LIF, ballot, store gm word ----
    {
      const int src = (b >> 1) * 4;
      const float r0 = __shfl(g2u0, src, 64);
      const float r1 = __shfl(g2u1, src, 64);
      const float g2m = (b & 1) ? r1 : r0;
      const float g1m = sm.g1buf[il][h * 32 + (b & 31)];
      const float I = __fadd_rn(g1m, g2m);
      v = __fadd_rn(__fmul_rn(0.9f, v), I);
      bool s = (b < 32) && (v >= 1.0f);
      if (s) { v = 0.f; cntr++; }
      unsigned long long bal = __ballot(s);   // low 32 bits = bats h*32..+31
      if (b == 0)
        __hip_atomic_store(gcur + iu * 2 + h, (unsigned)bal,
                           __ATOMIC_RELAXED, __HIP_MEMORY_SCOPE_AGENT);
    }
    __syncthreads();  // B: all waves' gm stores drained (vmcnt 0 at barrier)

    // ---- tid 0: tree arrival; last arriver raises 16 spread flags ----
    if (tid == 0) {
      unsigned old = __hip_atomic_fetch_add(cnt1, 1u, __ATOMIC_RELEASE,
                                            __HIP_MEMORY_SCOPE_AGENT);
      if (old == (unsigned)(t + 1) * GRPSZ - 1u) {
        unsigned old2 = __hip_atomic_fetch_add(cnt2, 1u, __ATOMIC_ACQ_REL,
                                               __HIP_MEMORY_SCOPE_AGENT);
        if (old2 == (unsigned)(t + 1) * NGRP - 1u) {
          #pragma unroll
          for (int f = 0; f < NFLAG; ++f)
            __hip_atomic_store(flgb + f * 256, (unsigned)(t + 1),
                               __ATOMIC_RELEASE, __HIP_MEMORY_SCOPE_AGENT);
        }
      }
    }

    // ---- classifier partials for s(t-1) -> clfred[t&1] (poll window) ----
    if (w < B_) {
      double pc[NCLS];
      #pragma unroll
      for (int c2 = 0; c2 < NCLS; ++c2) pc[c2] = 0.0;
      if (t > 0) {
        const int j0 = tid * 2;
        unsigned mw = sm.mask[w][j0 >> 5];
        #pragma unroll
        for (int jj = 0; jj < 2; ++jj) {
          if ((mw >> ((j0 + jj) & 31)) & 1u) {
            #pragma unroll
            for (int c2 = 0; c2 < NCLS; ++c2)
              pc[c2] += (double)wcf[c2 * 2 + jj];
          }
        }
      }
      #pragma unroll
      for (int off = 1; off < 64; off <<= 1) {
        #pragma unroll
        for (int c2 = 0; c2 < NCLS; ++c2)
          pc[c2] += __shfl_xor(pc[c2], off, 64);
      }
      if ((tid & 63) == 0) {
        #pragma unroll
        for (int c2 = 0; c2 < NCLS; ++c2) sm.clfred[t & 1][wid][c2] = pc[c2];
      }
    }

    // ---- classifier LIF: consume PREV step's partials (no barrier!) ----
    if (w < B_ && tid < NCLS && t >= 2) {
      double sc = 0.0;
      #pragma unroll
      for (int q2 = 0; q2 < 16; ++q2) sc += sm.clfred[(t + 1) & 1][q2][tid];
      vc = 0.9 * vc + sc;
      if (vc >= 1.0) { vc = 0.0; cntc++; }
    }

    // ---- stage xs(t+1) during the poll window ----
    if (t + 1 < T_) {
      const int p0 = tid * 8;
      #pragma unroll
      for (int r = 0; r < 8; ++r) {
        int p = p0 + r;
        sm.xs[p >> 7][p & 127] = xv[r];
      }
    }

    // ---- poll this wg's release flag ----
    if (tid == 0) {
      while (__hip_atomic_load(myflag, __ATOMIC_RELAXED,
                               __HIP_MEMORY_SCOPE_AGENT) < (unsigned)(t + 1))
        __builtin_amdgcn_s_sleep(1);
    }
    __syncthreads();  // D: whole wg proceeds past the grid barrier
  }

  // ======== epilogue ========
  // E1: deferred consume of partials written at t=499 (s(498), buf 1)
  if (w < B_ && tid < NCLS) {
    double sc = 0.0;
    #pragma unroll
    for (int q2 = 0; q2 < 16; ++q2) sc += sm.clfred[1][q2][tid];
    vc = 0.9 * vc + sc;
    if (vc >= 1.0) { vc = 0.0; cntc++; }
  }
  // E2: transpose s(499) (in gm1 since 499&1==1) -> sm.mask
  {
    const int i32 = b & 31, hh = b >> 5;
    #pragma unroll
    for (int kk = 0; kk < 4; ++kk) {
      const int k = (wid << 2) | kk;
      unsigned xw = __hip_atomic_load(gm1 + (k * 32 + i32) * 2 + hh,
                                      __ATOMIC_RELAXED, __HIP_MEMORY_SCOPE_AGENT);
      BT_ALL(xw);
      sm.mask[b][k] = xw;
    }
  }
  __syncthreads();
  // E3: classifier partials for s(499) -> clfred[0]
  if (w < B_) {
    double pc[NCLS];
    #pragma unroll
    for (int c2 = 0; c2 < NCLS; ++c2) pc[c2] = 0.0;
    const int j0 = tid * 2;
    unsigned mw = sm.mask[w][j0 >> 5];
    #pragma unroll
    for (int jj = 0; jj < 2; ++jj) {
      if ((mw >> ((j0 + jj) & 31)) & 1u) {
        #pragma unroll
        for (int c2 = 0; c2 < NCLS; ++c2)
          pc[c2] += (double)wcf[c2 * 2 + jj];
      }
    }
    #pragma unroll
    for (int off = 1; off < 64; off <<= 1) {
      #pragma unroll
      for (int c2 = 0; c2 < NCLS; ++c2)
        pc[c2] += __shfl_xor(pc[c2], off, 64);
    }
    if ((tid & 63) == 0) {
      #pragma unroll
      for (int c2 = 0; c2 < NCLS; ++c2) sm.clfred[0][wid][c2] = pc[c2];
    }
  }
  __syncthreads();
  // E4: final classifier LIF (s(499)) + output
  if (w < B_ && tid < NCLS) {
    double sc = 0.0;
    #pragma unroll
    for (int q2 = 0; q2 < 16; ++q2) sc += sm.clfred[0][q2][tid];
    vc = 0.9 * vc + sc;
    if (vc >= 1.0) cntc++;
    out[w * NCLS + tid] = (float)cntc;
  }
  // E5: reservoir spike counts: lane b<32 of wave (il,h) owns (h*32+b, iu)
  if (b < 32)
    out[B_ * NCLS + (size_t)(h * 32 + b) * NRES + w * SL + il] = (float)cntr;
}

extern "C" void kernel_launch(void* const* d_in, const int* in_sizes, int n_in,
                              void* d_out, int out_size, void* d_ws, size_t ws_size,
                              hipStream_t stream) {
  const float* x    = (const float*)d_in[0];   // (B, C, T)
  const float* Win  = (const float*)d_in[1];   // (NRES, C)
  const float* Wres = (const float*)d_in[2];   // (NRES, NRES)
  const float* Wclf = (const float*)d_in[3];   // (NCLS, NRES)
  float* out = (float*)d_out;
  unsigned char* ws = (unsigned char*)d_ws;

  hipLaunchKernelGGL(zero_ws_kernel, dim3((WS_WORDS + 255) / 256), dim3(256), 0, stream,
                     (unsigned*)ws, WS_WORDS);
  hipLaunchKernelGGL(reservoir_kernel, dim3(NWG), dim3(NT), 0, stream,
                     x, Win, Wres, Wclf, out, ws);
}

// Round 6
// 14030.624 us; speedup vs baseline: 1.6947x; 1.1338x over previous
//
#include <hip/hip_runtime.h>
#include <cstdint>
#include <cstddef>

// Problem constants (match reference)
#define B_    64
#define C_    128
#define T_    500
#define NRES  2048
#define NCLS  10

// Kernel org: 256 wgs (one per CU), 1024 threads = 16 waves.
// wid = tid>>6 ; il = wid&7 (neuron) ; h = wid>>3 (batch half).
// G2 transposed: lane l of wave (il,h): blk = l&3, g = l>>2; owns block blk
// of batches bat0 = h*32+2g, bat1 = bat0+1, packed in one v2f accumulator
// (element-wise IEEE RN adds — bit-exact per chain).
// G1: each wave, lanes 0..31: ascending fmaf chain for bat = h*32+lane
// (result stays in-register -> no g1buf, no barrier X).
#define NWG   256
#define SL    8
#define NT    1024
#define WROW  520              // skewed words per 512-block row
#define WPIT  (4 * WROW)       // words per neuron row in LDS

// BIT-EXACT MODEL (validated, absmax 0.0): G1: ascending fmaf chain (K=128).
// G2: KC=512 blocks [512,512,512,512], each an ascending masked rn-add chain
// starting at 0, folded left-to-right ((b0+b1)+b2)+b3.
// LIF: v = rn(rn(0.9f*v) + rn(g1+g2)). DO NOT CHANGE THE ARITHMETIC.

// r6 sync redesign (r5 residual ~8-12 us/step in barrier/straggler path):
//  - FLAT ARRIVAL: wg w RELEASE-stores t+1 to its own 16-B slot (parallel,
//    no RMW chain). Wave 0 of wg 255 polls all 256 slots (4 loads/lane),
//    then raises 16 spread release flags. Replaces the 2-level counter tree
//    whose level-1 was 32 serialized same-line RMWs.
//  - barrier X removed (per-wave G1, g1 in-register).
//  - xs double-buffered: staging overlaps compute after barrier A; the poll
//    window is empty for non-classifier wgs.
//  - classifier: one wave per class (wid<10), Wclf read from global
//    (L2-resident 80 KB), 6 f64 shfls/wave instead of 120 x 16 waves;
//    clfred2 = one double per class, vc update reads a single value.

// d_ws layout
#define WS_MASK0   0            // 16 KB: gm buf0 (4096 words: j*2+h)
#define WS_MASK1   16384        // 16 KB: gm buf1
#define WS_FLAG    32768        // 16 flags, 1024 B apart (16 KB)
#define WS_ARR     49152        // 256 arrival slots, 16 B apart (4 KB)
#define WS_WORDS   13312        // zero through 53248 B
#define NFLAG      16
#define CHKWG      (NWG - 1)

typedef float v2f __attribute__((ext_vector_type(2)));

struct SMem {
  float    WtT2[SL][WPIT];          // 66560 B : skewed W_res rows
  float    WinT2[SL][C_];           //  4096 B : W_in rows
  float    xs2[2][B_][C_ + 1];      // 66048 B : x[:, :, t], double-buffered
  unsigned mask[B_][65];            // 16640 B : bat-major spike words s(t-1)
  double   clfred2[2][NCLS];        //   160 B : per-class partials, 2 bufs
};                                   // total 153504 B => 1 wg/CU (grid = 256)

__global__ void zero_ws_kernel(unsigned* __restrict__ p, int n) {
  int i = blockIdx.x * blockDim.x + threadIdx.x;
  if (i < n) p[i] = 0u;
}

// packed masked add: lanes' bat0/bat1 chains advance together.
// bfe(sign-extend bit)x2 + and x2 + <2 x float> fadd (RN per elem, bit-exact).
#define ACC2(ACC, WB, M0, M1, JB) do {                                        \
  const unsigned _lo = (unsigned)(((int)((M0) << (31 - (JB)))) >> 31) & (WB); \
  const unsigned _hi = (unsigned)(((int)((M1) << (31 - (JB)))) >> 31) & (WB); \
  v2f _m; _m.x = __uint_as_float(_lo); _m.y = __uint_as_float(_hi);           \
  (ACC) = (ACC) + _m;                                                         \
} while (0)

// one step of the 32x32 bit-matrix transpose ladder (periodic masks):
// element view: A'[r][c] = (r&D)==(c&D) ? A[r][c] : A[r^D][c^D]
#define BT_STEP(X, D, MLO) do {                                            \
  const unsigned _y = (unsigned)__shfl_xor((int)(X), (D), 64);             \
  (X) = (b & (D)) ? (((X) & ~(MLO)) | ((_y >> (D)) & (MLO)))               \
                  : (((X) & (MLO)) | ((_y << (D)) & ~(MLO)));              \
} while (0)

#define BT_ALL(X) do {                 \
  BT_STEP(X, 16, 0x0000FFFFu);         \
  BT_STEP(X,  8, 0x00FF00FFu);         \
  BT_STEP(X,  4, 0x0F0F0F0Fu);         \
  BT_STEP(X,  2, 0x33333333u);         \
  BT_STEP(X,  1, 0x55555555u);         \
} while (0)

__global__ void __launch_bounds__(NT, 4)
reservoir_kernel(const float* __restrict__ x, const float* __restrict__ Win,
                 const float* __restrict__ Wres, const float* __restrict__ Wclf,
                 float* __restrict__ out, unsigned char* __restrict__ ws) {
  __shared__ SMem sm;
  const int w   = blockIdx.x;
  const int tid = threadIdx.x;
  const int b   = tid & 63;          // lane index
  const int wid = tid >> 6;          // wave index 0..15
  const int il  = wid & 7;           // neuron within wg
  const int h   = wid >> 3;          // batch half
  const int blk = b & 3;             // G2: block owned by this lane
  const int g   = b >> 2;            // G2: batch pair group
  const int bat0 = h * 32 + g * 2;
  const int bat1 = bat0 + 1;
  const int iu  = __builtin_amdgcn_readfirstlane(w * SL + il);

  unsigned* gm0  = (unsigned*)(ws + WS_MASK0);
  unsigned* gm1  = (unsigned*)(ws + WS_MASK1);
  unsigned* flgb = (unsigned*)(ws + WS_FLAG);
  unsigned* arr  = (unsigned*)(ws + WS_ARR);
  unsigned* myflag = flgb + (w & (NFLAG - 1)) * 256;   // 1024-B spacing

  // ---- one-time: stage skewed W_res rows (16 float4 per thread) ----
  {
    const int j0 = tid * 16;
    #pragma unroll
    for (int r4 = 0; r4 < 4; ++r4) {
      const int j   = j0 + r4 * 4;
      const int il2 = j >> 11;
      const int pos = j & 2047;
      const int bk  = pos >> 9;
      const int s   = pos & 511;
      const float4 v4 = *(const float4*)(Wres + (size_t)(w * SL + il2) * NRES + pos);
      *(float4*)(&sm.WtT2[il2][bk * WROW + s]) = v4;
    }
  }
  {
    const int il2 = tid >> 7, c = tid & 127;
    sm.WinT2[il2][c] = Win[(size_t)(w * SL + il2) * C_ + c];
  }

  float v = 0.f;                   // reservoir membrane (lanes b<32)
  int   cntr = 0;
  double vc = 0.0;                 // classifier membrane
  int   cntc = 0;

  // prologue: stage xs(0) into buf0; prefetch x(:,:,1) into xv
  float xv[8];
  {
    const int p0 = tid * 8;
    #pragma unroll
    for (int r = 0; r < 8; ++r) {
      float z = x[(size_t)(p0 + r) * T_ + 0];
      int p = p0 + r;
      sm.xs2[0][p >> 7][p & 127] = z;
    }
    #pragma unroll
    for (int r = 0; r < 8; ++r) xv[r] = x[(size_t)(p0 + r) * T_ + 1];
  }

  for (int t = 0; t < T_; ++t) {
    unsigned* gprev = (t & 1) ? gm0 : gm1;   // s(t-1); t=0 reads zeroed gm1
    unsigned* gcur  = (t & 1) ? gm1 : gm0;

    // ---- load neuron-major ballots + 64x64 bit transpose -> sm.mask ----
    {
      const int i32 = b & 31, hh = b >> 5;
      #pragma unroll
      for (int kk = 0; kk < 4; ++kk) {
        const int k = (wid << 2) | kk;
        unsigned xw = __hip_atomic_load(gprev + (k * 32 + i32) * 2 + hh,
                                        __ATOMIC_RELAXED, __HIP_MEMORY_SCOPE_AGENT);
        BT_ALL(xw);
        sm.mask[b][k] = xw;
      }
    }
    __syncthreads();  // A: mask + xs(t) ready (also guards one-time stages)

    // ---- stage xs(t+1) into the other buffer (overlaps compute) ----
    if (t + 1 < T_) {
      const int p0 = tid * 8;
      #pragma unroll
      for (int r = 0; r < 8; ++r) {
        int p = p0 + r;
        sm.xs2[(t + 1) & 1][p >> 7][p & 127] = xv[r];
      }
      if (t + 2 < T_) {
        #pragma unroll
        for (int r = 0; r < 8; ++r) xv[r] = x[(size_t)(p0 + r) * T_ + (t + 2)];
      }
    }

    // ---- G1 (all waves, lanes 0..31): ascending fmaf chain, bat=h*32+b ----
    float g1 = 0.f;
    if (b < 32) {
      const int bat = h * 32 + b;
      const float4* __restrict__ winp = (const float4*)&sm.WinT2[il][0];
      const float* __restrict__ xrow = &sm.xs2[t & 1][bat][0];
      #pragma unroll 8
      for (int cq = 0; cq < 32; ++cq) {
        const float4 wv = winp[cq];
        const int c = cq * 4;
        g1 = fmaf(xrow[c + 0], wv.x, g1);
        g1 = fmaf(xrow[c + 1], wv.y, g1);
        g1 = fmaf(xrow[c + 2], wv.z, g1);
        g1 = fmaf(xrow[c + 3], wv.w, g1);
      }
    }

    // ---- G2 transposed + packed: block blk of bat0 (lo) and bat1 (hi) ----
    v2f acc; acc.x = 0.f; acc.y = 0.f;
    {
      const float*    wbase = &sm.WtT2[il][blk * WROW];
      const unsigned* mr0   = &sm.mask[bat0][blk * 16];
      const unsigned* mr1   = &sm.mask[bat1][blk * 16];
      for (int wq = 0; wq < 16; ++wq) {
        const unsigned m0 = mr0[wq];
        const unsigned m1 = mr1[wq];
        const float4* q = (const float4*)(wbase + wq * 32);
        #pragma unroll
        for (int jq = 0; jq < 8; ++jq) {
          const float4 w4 = q[jq];
          const int jb = jq * 4;
          ACC2(acc, __float_as_uint(w4.x), m0, m1, jb + 0);
          ACC2(acc, __float_as_uint(w4.y), m0, m1, jb + 1);
          ACC2(acc, __float_as_uint(w4.z), m0, m1, jb + 2);
          ACC2(acc, __float_as_uint(w4.w), m0, m1, jb + 3);
        }
      }
    }
    const float aP = acc.x, aQ = acc.y;

    // ---- intra-wave fold to blk0 lanes: ((b0+b1)+b2)+b3 exact order ----
    const float p1 = __shfl_xor(aP, 1), q1 = __shfl_xor(aQ, 1);
    const float p2 = __shfl_xor(aP, 2), q2 = __shfl_xor(aQ, 2);
    const float p3 = __shfl_xor(aP, 3), q3 = __shfl_xor(aQ, 3);
    const float g2u0 = __fadd_rn(__fadd_rn(__fadd_rn(aP, p1), p2), p3);
    const float g2u1 = __fadd_rn(__fadd_rn(__fadd_rn(aQ, q1), q2), q3);

    // ---- redistribute to lane=bat (b<32), LIF, ballot, store gm word ----
    {
      const int src = (b >> 1) * 4;
      const float r0 = __shfl(g2u0, src, 64);
      const float r1 = __shfl(g2u1, src, 64);
      const float g2m = (b & 1) ? r1 : r0;
      const float I = __fadd_rn(g1, g2m);
      v = __fadd_rn(__fmul_rn(0.9f, v), I);
      bool s = (b < 32) && (v >= 1.0f);
      if (s) { v = 0.f; cntr++; }
      unsigned long long bal = __ballot(s);   // low 32 bits = bats h*32..+31
      if (b == 0)
        __hip_atomic_store(gcur + iu * 2 + h, (unsigned)bal,
                           __ATOMIC_RELAXED, __HIP_MEMORY_SCOPE_AGENT);
    }
    __syncthreads();  // B: all waves' gm stores drained (vmcnt 0 at barrier)

    // ---- FLAT ARRIVAL: own slot, release store (orders the gm stores) ----
    if (tid == 0)
      __hip_atomic_store(arr + w * 4, (unsigned)(t + 1),
                         __ATOMIC_RELEASE, __HIP_MEMORY_SCOPE_AGENT);

    // ---- CHECKER (wg 255, wave 0): poll all 256 slots, then release ----
    if (w == CHKWG && wid == 0) {
      const unsigned tgt = (unsigned)(t + 1);
      for (;;) {
        unsigned a0 = __hip_atomic_load(arr + (b +   0) * 4, __ATOMIC_RELAXED,
                                        __HIP_MEMORY_SCOPE_AGENT);
        unsigned a1 = __hip_atomic_load(arr + (b +  64) * 4, __ATOMIC_RELAXED,
                                        __HIP_MEMORY_SCOPE_AGENT);
        unsigned a2 = __hip_atomic_load(arr + (b + 128) * 4, __ATOMIC_RELAXED,
                                        __HIP_MEMORY_SCOPE_AGENT);
        unsigned a3 = __hip_atomic_load(arr + (b + 192) * 4, __ATOMIC_RELAXED,
                                        __HIP_MEMORY_SCOPE_AGENT);
        bool ok = (a0 >= tgt) & (a1 >= tgt) & (a2 >= tgt) & (a3 >= tgt);
        if (__all(ok)) break;
        __builtin_amdgcn_s_sleep(1);
      }
      if (b < NFLAG)
        __hip_atomic_store(flgb + b * 256, (unsigned)(t + 1),
                           __ATOMIC_RELEASE, __HIP_MEMORY_SCOPE_AGENT);
    }

    // ---- classifier partials for s(t-1): wave wid<10 = class wid (wg<64) ----
    if (w < B_ && wid < NCLS) {
      double pc = 0.0;
      if (t > 0) {
        const float* __restrict__ wc = Wclf + (size_t)wid * NRES + b;
        #pragma unroll 4
        for (int q = 0; q < 32; ++q) {
          const unsigned mw = sm.mask[w][(b >> 5) + 2 * q];
          const float wv = wc[q * 64];
          const unsigned keep =
              (unsigned)(((int)(mw << (31 - (b & 31)))) >> 31);
          pc += (double)__uint_as_float(keep & __float_as_uint(wv));
        }
      }
      #pragma unroll
      for (int off = 1; off < 64; off <<= 1)
        pc += __shfl_xor(pc, off, 64);
      if (b == 0) sm.clfred2[t & 1][wid] = pc;
    }

    // ---- classifier LIF: consume PREV step's partial (single value) ----
    if (w < B_ && tid < NCLS && t >= 2) {
      vc = 0.9 * vc + sm.clfred2[(t + 1) & 1][tid];
      if (vc >= 1.0) { vc = 0.0; cntc++; }
    }

    // ---- poll this wg's release flag ----
    if (tid == 0) {
      while (__hip_atomic_load(myflag, __ATOMIC_RELAXED,
                               __HIP_MEMORY_SCOPE_AGENT) < (unsigned)(t + 1))
        __builtin_amdgcn_s_sleep(1);
    }
    __syncthreads();  // D: whole wg proceeds past the grid barrier
  }

  // ======== epilogue ========
  // E1: deferred consume of partials written at t=499 (s(498), buf 1)
  if (w < B_ && tid < NCLS) {
    vc = 0.9 * vc + sm.clfred2[1][tid];
    if (vc >= 1.0) { vc = 0.0; cntc++; }
  }
  // E2: transpose s(499) (in gm1 since 499&1==1) -> sm.mask
  {
    const int i32 = b & 31, hh = b >> 5;
    #pragma unroll
    for (int kk = 0; kk < 4; ++kk) {
      const int k = (wid << 2) | kk;
      unsigned xw = __hip_atomic_load(gm1 + (k * 32 + i32) * 2 + hh,
                                      __ATOMIC_RELAXED, __HIP_MEMORY_SCOPE_AGENT);
      BT_ALL(xw);
      sm.mask[b][k] = xw;
    }
  }
  __syncthreads();
  // E3: classifier partials for s(499) -> clfred2[0]
  if (w < B_ && wid < NCLS) {
    double pc = 0.0;
    {
      const float* __restrict__ wc = Wclf + (size_t)wid * NRES + b;
      #pragma unroll 4
      for (int q = 0; q < 32; ++q) {
        const unsigned mw = sm.mask[w][(b >> 5) + 2 * q];
        const float wv = wc[q * 64];
        const unsigned keep =
            (unsigned)(((int)(mw << (31 - (b & 31)))) >> 31);
        pc += (double)__uint_as_float(keep & __float_as_uint(wv));
      }
    }
    #pragma unroll
    for (int off = 1; off < 64; off <<= 1)
      pc += __shfl_xor(pc, off, 64);
    if (b == 0) sm.clfred2[0][wid] = pc;
  }
  __syncthreads();
  // E4: final classifier LIF (s(499)) + output
  if (w < B_ && tid < NCLS) {
    vc = 0.9 * vc + sm.clfred2[0][tid];
    if (vc >= 1.0) cntc++;
    out[w * NCLS + tid] = (float)cntc;
  }
  // E5: reservoir spike counts: lane b<32 of wave (il,h) owns (h*32+b, iu)
  if (b < 32)
    out[B_ * NCLS + (size_t)(h * 32 + b) * NRES + w * SL + il] = (float)cntr;
}

extern "C" void kernel_launch(void* const* d_in, const int* in_sizes, int n_in,
                              void* d_out, int out_size, void* d_ws, size_t ws_size,
                              hipStream_t stream) {
  const float* x    = (const float*)d_in[0];   // (B, C, T)
  const float* Win  = (const float*)d_in[1];   // (NRES, C)
  const float* Wres = (const float*)d_in[2];   // (NRES, NRES)
  const float* Wclf = (const float*)d_in[3];   // (NCLS, NRES)
  float* out = (float*)d_out;
  unsigned char* ws = (unsigned char*)d_ws;

  hipLaunchKernelGGL(zero_ws_kernel, dim3((WS_WORDS + 255) / 256), dim3(256), 0, stream,
                     (unsigned*)ws, WS_WORDS);
  hipLaunchKernelGGL(reservoir_kernel, dim3(NWG), dim3(NT), 0, stream,
                     x, Win, Wres, Wclf, out, ws);
}